// Round 2
// baseline (310.775 us; speedup 1.0000x reference)
//
#include <hip/hip_runtime.h>

typedef __bf16 bf16;
typedef __bf16 bf16x4 __attribute__((ext_vector_type(4)));
typedef __bf16 bf16x8 __attribute__((ext_vector_type(8)));
typedef float f32x4 __attribute__((ext_vector_type(4)));

#define AS1 __attribute__((address_space(1)))
#define AS3 __attribute__((address_space(3)))

__device__ __forceinline__ void async_copy16(const void* g, void* l) {
  // global -> LDS direct, 16B/lane; LDS dest = wave-uniform base + lane*16.
  __builtin_amdgcn_global_load_lds((const AS1 void*)g, (AS3 void*)l, 16, 0, 0);
}

#define BB 8
#define CC 1024
#define QQ 128
#define EE 512
#define HH 1024
#define FOURE 2048

// ---------------------------------------------------------------------------
// prep: three f32->bf16 transposes in one launch.
//  bx [0,2048):    W1 (2048x1024) -> W1T (1024x2048)
//  bx [2048,4096): W2 (1024x2048) -> W2T (2048x1024)
//  bx [4096,4608): question per-batch (128x512) -> qT (512x128)
// ---------------------------------------------------------------------------
__global__ __launch_bounds__(256) void prep_kernel(
    const float* __restrict__ W1, const float* __restrict__ W2,
    const float* __restrict__ qst, bf16* __restrict__ W1T,
    bf16* __restrict__ W2T, bf16* __restrict__ qT) {
  __shared__ float tile[32][33];
  int bx = blockIdx.x;
  const float* src;
  bf16* dst;
  int R, C, idx;
  if (bx < 2048) {
    src = W1; dst = W1T; R = 2048; C = 1024; idx = bx;
  } else if (bx < 4096) {
    src = W2; dst = W2T; R = 1024; C = 2048; idx = bx - 2048;
  } else {
    int i = bx - 4096;
    int b = i >> 6; idx = i & 63;
    src = qst + (size_t)b * QQ * EE; dst = qT + (size_t)b * EE * QQ;
    R = 128; C = 512;
  }
  int ctiles = C >> 5;
  int by = idx / ctiles, cx = idx % ctiles;
  int tx = threadIdx.x & 31, ty = threadIdx.x >> 5;
#pragma unroll
  for (int rr = 0; rr < 4; ++rr)
    tile[ty + rr * 8][tx] = src[(size_t)(by * 32 + ty + rr * 8) * C + cx * 32 + tx];
  __syncthreads();
#pragma unroll
  for (int rr = 0; rr < 4; ++rr)
    dst[(size_t)(cx * 32 + ty + rr * 8) * R + by * 32 + tx] = (bf16)tile[tx][ty + rr * 8];
}

// ---------------------------------------------------------------------------
// sim: sim[b,c,q] = sum_e ctx*(qst*wmul) + qw[q] + cw[c], split-bf16 (3 MFMA)
// for fp32-grade accuracy. Fuses the rowdot: cw/qw accumulated during staging.
// Tile 64(M=c) x 128(N=q), BK=32, grid 16x8 = 128 blocks.
// ---------------------------------------------------------------------------
__global__ __launch_bounds__(256) void sim_kernel(
    const float* __restrict__ ctx, const float* __restrict__ qst,
    const float* __restrict__ wq, const float* __restrict__ wc,
    const float* __restrict__ wmul, float* __restrict__ sim) {
  int b = blockIdx.y;
  int m0 = blockIdx.x * 64;
  __shared__ bf16 Ah[64 * 32], Al[64 * 32], Bh[128 * 32], Bl[128 * 32];
  __shared__ float wq_s[EE], wc_s[EE], wm_s[EE];
  __shared__ float cw_s[64], qw_s[128];
  int t = threadIdx.x;
  for (int i = t; i < EE; i += 256) {
    wq_s[i] = wq[i]; wc_s[i] = wc[i]; wm_s[i] = wmul[i];
  }
  __syncthreads();
  int wv = t >> 6, ln = t & 63, wm = wv >> 1, wn = wv & 1;
  f32x4 acc[2][4] = {};
  const float* Ag = ctx + ((size_t)b * CC + m0) * EE;
  const float* Bg = qst + (size_t)b * QQ * EE;
  int arow = t >> 2, acq = t & 3;         // A: 8 elems/thread
  int brow = t >> 1, bcq0 = (t & 1) * 2;  // B: 16 elems/thread (2 chunks)
  float cwp = 0.f, qwp = 0.f;
  for (int k0 = 0; k0 < EE; k0 += 32) {
    {  // stage A (ctx rows) hi/lo, chunk-swizzled
      const float4* s4 = (const float4*)(Ag + (size_t)arow * EE + k0 + acq * 8);
      float4 v0 = s4[0], v1 = s4[1];
      float vals[8] = {v0.x, v0.y, v0.z, v0.w, v1.x, v1.y, v1.z, v1.w};
      bf16x8 h, l;
#pragma unroll
      for (int i = 0; i < 8; ++i) {
        cwp += vals[i] * wc_s[k0 + acq * 8 + i];
        bf16 hh = (bf16)vals[i];
        h[i] = hh; l[i] = (bf16)(vals[i] - (float)hh);
      }
      int sl = (acq ^ ((arow >> 1) & 3)) * 8;
      *(bf16x8*)&Ah[arow * 32 + sl] = h;
      *(bf16x8*)&Al[arow * 32 + sl] = l;
    }
#pragma unroll
    for (int cc = 0; cc < 2; ++cc) {  // stage B (question*wmul) hi/lo
      int cq = bcq0 + cc;
      const float4* s4 = (const float4*)(Bg + (size_t)brow * EE + k0 + cq * 8);
      float4 v0 = s4[0], v1 = s4[1];
      float vals[8] = {v0.x, v0.y, v0.z, v0.w, v1.x, v1.y, v1.z, v1.w};
      bf16x8 h, l;
#pragma unroll
      for (int i = 0; i < 8; ++i) {
        qwp += vals[i] * wq_s[k0 + cq * 8 + i];
        float sv = vals[i] * wm_s[k0 + cq * 8 + i];
        bf16 hh = (bf16)sv;
        h[i] = hh; l[i] = (bf16)(sv - (float)hh);
      }
      int sl = (cq ^ ((brow >> 1) & 3)) * 8;
      *(bf16x8*)&Bh[brow * 32 + sl] = h;
      *(bf16x8*)&Bl[brow * 32 + sl] = l;
    }
    __syncthreads();
    int rl = ln & 15, kq = ln >> 4;
    bf16x8 ah[2], al[2], bh[4], bl[4];
#pragma unroll
    for (int i = 0; i < 2; ++i) {
      int r = wm * 32 + i * 16 + rl;
      int sl = (kq ^ ((r >> 1) & 3)) * 8;
      ah[i] = *(const bf16x8*)&Ah[r * 32 + sl];
      al[i] = *(const bf16x8*)&Al[r * 32 + sl];
    }
#pragma unroll
    for (int j = 0; j < 4; ++j) {
      int r = wn * 64 + j * 16 + rl;
      int sl = (kq ^ ((r >> 1) & 3)) * 8;
      bh[j] = *(const bf16x8*)&Bh[r * 32 + sl];
      bl[j] = *(const bf16x8*)&Bl[r * 32 + sl];
    }
#pragma unroll
    for (int i = 0; i < 2; ++i)
#pragma unroll
      for (int j = 0; j < 4; ++j) {
        acc[i][j] = __builtin_amdgcn_mfma_f32_16x16x32_bf16(ah[i], bh[j], acc[i][j], 0, 0, 0);
        acc[i][j] = __builtin_amdgcn_mfma_f32_16x16x32_bf16(ah[i], bl[j], acc[i][j], 0, 0, 0);
        acc[i][j] = __builtin_amdgcn_mfma_f32_16x16x32_bf16(al[i], bh[j], acc[i][j], 0, 0, 0);
      }
    __syncthreads();
  }
  // fused rowdot reduction: cw (4 lanes/row), qw (2 lanes/row)
  float s = cwp;
  s += __shfl_xor(s, 1); s += __shfl_xor(s, 2);
  if ((t & 3) == 0) cw_s[arow] = s;
  float s2 = qwp;
  s2 += __shfl_xor(s2, 1);
  if (!(t & 1)) qw_s[brow] = s2;
  __syncthreads();
  float* simb = sim + ((size_t)b * CC + m0) * QQ;
#pragma unroll
  for (int j = 0; j < 4; ++j) {
    int col = wn * 64 + j * 16 + (ln & 15);
    float qv = qw_s[col];
#pragma unroll
    for (int i = 0; i < 2; ++i) {
      int rbase = wm * 32 + i * 16 + ((ln >> 4) << 2);
#pragma unroll
      for (int r = 0; r < 4; ++r) {
        int rowl = rbase + r;
        simb[(size_t)rowl * QQ + col] = acc[i][j][r] + qv + cw_s[rowl];
      }
    }
  }
}

// ---------------------------------------------------------------------------
// softmax over q (128) per (b,c) row; one wave/row. P bf16 + row max.
// ---------------------------------------------------------------------------
__global__ __launch_bounds__(256) void softmax_q_kernel(
    const float* __restrict__ sim, bf16* __restrict__ P, float* __restrict__ smax) {
  int row = blockIdx.x * 4 + (threadIdx.x >> 6);
  int ln = threadIdx.x & 63;
  const float* s = sim + (size_t)row * QQ;
  float v0 = s[ln], v1 = s[64 + ln];
  float mx = fmaxf(v0, v1);
#pragma unroll
  for (int off = 32; off; off >>= 1) mx = fmaxf(mx, __shfl_xor(mx, off));
  float e0 = __expf(v0 - mx), e1 = __expf(v1 - mx);
  float sm = e0 + e1;
#pragma unroll
  for (int off = 32; off; off >>= 1) sm += __shfl_xor(sm, off);
  float inv = 1.0f / sm;
  P[(size_t)row * QQ + ln] = (bf16)(e0 * inv);
  P[(size_t)row * QQ + 64 + ln] = (bf16)(e1 * inv);
  if (ln == 0) smax[row] = mx;
}

// ---------------------------------------------------------------------------
// q2c (with softmax over c fused, redundantly per block — trivial cost):
// q2c[b,e] = sum_c softmax_c(smax)[b,c] * ctx[b,c,e].  Grid 64 = 8b x 8 egroups.
// ---------------------------------------------------------------------------
__global__ __launch_bounds__(256) void q2c_kernel(
    const float* __restrict__ ctx, const float* __restrict__ smax,
    float* __restrict__ q2c) {
  int b = blockIdx.x >> 3, g = blockIdx.x & 7;
  int t = threadIdx.x;
  __shared__ float red[256];
  __shared__ float cwt_s[CC];
  float v[4];
  float mx = -3.4e38f;
#pragma unroll
  for (int i = 0; i < 4; ++i) {
    v[i] = smax[b * CC + i * 256 + t];
    mx = fmaxf(mx, v[i]);
  }
  red[t] = mx;
  __syncthreads();
  for (int s = 128; s > 0; s >>= 1) {
    if (t < s) red[t] = fmaxf(red[t], red[t + s]);
    __syncthreads();
  }
  mx = red[0];
  __syncthreads();
  float ex[4], sm = 0.f;
#pragma unroll
  for (int i = 0; i < 4; ++i) { ex[i] = __expf(v[i] - mx); sm += ex[i]; }
  red[t] = sm;
  __syncthreads();
  for (int s = 128; s > 0; s >>= 1) {
    if (t < s) red[t] += red[t + s];
    __syncthreads();
  }
  float inv = 1.0f / red[0];
#pragma unroll
  for (int i = 0; i < 4; ++i) cwt_s[i * 256 + t] = ex[i] * inv;
  __syncthreads();
  int e = g * 64 + (t & 63), cq = t >> 6;
  float acc = 0.f;
  const float* cb = ctx + (size_t)b * CC * EE;
  for (int c = cq * 256; c < cq * 256 + 256; ++c)
    acc += cwt_s[c] * cb[(size_t)c * EE + e];
  red[cq * 64 + (t & 63)] = acc;
  __syncthreads();
  if (cq == 0)
    q2c[b * EE + e] = red[t] + red[64 + t] + red[128 + t] + red[192 + t];
}

// ---------------------------------------------------------------------------
// Unified bf16 GEMM: C = A(MxK) @ Bt(NxK)^T. Tile MT x 128, BK=64,
// global_load_lds 16B staging with XOR chunk-swizzle (chunk ^= row&7),
// 16x16x32 bf16 MFMA. K % 64 == 0.
// ---------------------------------------------------------------------------
template <int MT, int OUT_BF16, int RELU, int HAS_BIAS, int HAS_MASK>
__global__ __launch_bounds__(256) void gemm_bt_kernel(
    const bf16* __restrict__ A, const bf16* __restrict__ Bt,
    const float* __restrict__ bias, const float* __restrict__ mask,
    void* __restrict__ Cout, int M, int N, int K, long sA, long sB, long sC) {
  int b = blockIdx.y;
  A += (size_t)b * sA;
  Bt += (size_t)b * sB;
  int ntiles = N >> 7;
  int mt = blockIdx.x / ntiles, ntb = blockIdx.x % ntiles;
  int m0 = mt * MT, n0 = ntb << 7;
  __shared__ bf16 As[MT * 64];
  __shared__ bf16 Bs[128 * 64];
  int t = threadIdx.x, wv = t >> 6, ln = t & 63;
  int wm = wv >> 1, wn = wv & 1;
  constexpr int MI = MT / 32;
  f32x4 acc[MI][4] = {};
  for (int k0 = 0; k0 < K; k0 += 64) {
#pragma unroll
    for (int r = 0; r < MT / 32; ++r) {
      int fb = (r * 4 + wv) * 1024 + ln * 16;
      int row = fb >> 7;
      int q = ((fb >> 4) & 7) ^ (row & 7);
      async_copy16(A + (size_t)(m0 + row) * K + k0 + q * 8,
                   (char*)As + (r * 4 + wv) * 1024);
    }
#pragma unroll
    for (int r = 0; r < 4; ++r) {
      int fb = (r * 4 + wv) * 1024 + ln * 16;
      int row = fb >> 7;
      int q = ((fb >> 4) & 7) ^ (row & 7);
      async_copy16(Bt + (size_t)(n0 + row) * K + k0 + q * 8,
                   (char*)Bs + (r * 4 + wv) * 1024);
    }
    __syncthreads();
    int rl = ln & 15, kq = ln >> 4;
#pragma unroll
    for (int ks = 0; ks < 2; ++ks) {
      int c = ks * 4 + kq;
      bf16x8 af[MI], bfr[4];
#pragma unroll
      for (int i = 0; i < MI; ++i) {
        int row = wm * (MT / 2) + i * 16 + rl;
        af[i] = *(const bf16x8*)&As[row * 64 + ((c ^ (row & 7)) * 8)];
      }
#pragma unroll
      for (int j = 0; j < 4; ++j) {
        int row = wn * 64 + j * 16 + rl;
        bfr[j] = *(const bf16x8*)&Bs[row * 64 + ((c ^ (row & 7)) * 8)];
      }
#pragma unroll
      for (int i = 0; i < MI; ++i)
#pragma unroll
        for (int j = 0; j < 4; ++j)
          acc[i][j] = __builtin_amdgcn_mfma_f32_16x16x32_bf16(af[i], bfr[j], acc[i][j], 0, 0, 0);
    }
    __syncthreads();
  }
  size_t outbase = (size_t)b * sC;
#pragma unroll
  for (int j = 0; j < 4; ++j) {
    int col = n0 + wn * 64 + j * 16 + (ln & 15);
    float bv = HAS_BIAS ? bias[col] : 0.f;
#pragma unroll
    for (int i = 0; i < MI; ++i) {
      int rbase = m0 + wm * (MT / 2) + i * 16 + ((ln >> 4) << 2);
#pragma unroll
      for (int r = 0; r < 4; ++r) {
        int row = rbase + r;
        float v = acc[i][j][r] + bv;
        if (HAS_MASK) v *= mask[row];
        if (RELU) v = fmaxf(v, 0.f);
        if (OUT_BF16)
          ((bf16*)Cout)[outbase + (size_t)row * N + col] = (bf16)v;
        else
          ((float*)Cout)[outbase + (size_t)row * N + col] = v;
      }
    }
  }
}

// ---------------------------------------------------------------------------
// c2q GEMM (P @ question) with fused attended-build epilogue:
// writes att = [ctx | c2q | ctx*c2q | ctx*q2c] directly. Tile 128x128, K=128.
// ---------------------------------------------------------------------------
__global__ __launch_bounds__(256) void c2q_att_kernel(
    const bf16* __restrict__ P, const bf16* __restrict__ qT,
    const float* __restrict__ ctx, const float* __restrict__ q2c,
    bf16* __restrict__ att) {
  int b = blockIdx.y;
  const bf16* A = P + (size_t)b * CC * QQ;
  const bf16* Bt = qT + (size_t)b * EE * QQ;
  int mt = blockIdx.x >> 2, ntb = blockIdx.x & 3;
  int m0 = mt << 7, n0 = ntb << 7;
  __shared__ bf16 As[128 * 64];
  __shared__ bf16 Bs[128 * 64];
  int t = threadIdx.x, wv = t >> 6, ln = t & 63;
  int wm = wv >> 1, wn = wv & 1;
  f32x4 acc[4][4] = {};
  for (int k0 = 0; k0 < QQ; k0 += 64) {
#pragma unroll
    for (int r = 0; r < 4; ++r) {
      int fb = (r * 4 + wv) * 1024 + ln * 16;
      int row = fb >> 7;
      int q = ((fb >> 4) & 7) ^ (row & 7);
      async_copy16(A + (size_t)(m0 + row) * QQ + k0 + q * 8,
                   (char*)As + (r * 4 + wv) * 1024);
      async_copy16(Bt + (size_t)(n0 + row) * QQ + k0 + q * 8,
                   (char*)Bs + (r * 4 + wv) * 1024);
    }
    __syncthreads();
    int rl = ln & 15, kq = ln >> 4;
#pragma unroll
    for (int ks = 0; ks < 2; ++ks) {
      int c = ks * 4 + kq;
      bf16x8 af[4], bfr[4];
#pragma unroll
      for (int i = 0; i < 4; ++i) {
        int row = wm * 64 + i * 16 + rl;
        af[i] = *(const bf16x8*)&As[row * 64 + ((c ^ (row & 7)) * 8)];
      }
#pragma unroll
      for (int j = 0; j < 4; ++j) {
        int row = wn * 64 + j * 16 + rl;
        bfr[j] = *(const bf16x8*)&Bs[row * 64 + ((c ^ (row & 7)) * 8)];
      }
#pragma unroll
      for (int i = 0; i < 4; ++i)
#pragma unroll
        for (int j = 0; j < 4; ++j)
          acc[i][j] = __builtin_amdgcn_mfma_f32_16x16x32_bf16(af[i], bfr[j], acc[i][j], 0, 0, 0);
    }
    __syncthreads();
  }
  const float* ctxb = ctx + (size_t)b * CC * EE;
  const float* q2cb = q2c + (size_t)b * EE;
  bf16* attb = att + (size_t)b * CC * FOURE;
#pragma unroll
  for (int j = 0; j < 4; ++j) {
    int col = n0 + wn * 64 + j * 16 + (ln & 15);
    float qv = q2cb[col];
#pragma unroll
    for (int i = 0; i < 4; ++i) {
      int rbase = m0 + wm * 64 + i * 16 + ((ln >> 4) << 2);
#pragma unroll
      for (int r = 0; r < 4; ++r) {
        int row = rbase + r;
        float cv = ctxb[(size_t)row * EE + col];
        float p = acc[i][j][r];
        bf16* d = attb + (size_t)row * FOURE;
        d[col] = (bf16)cv;
        d[EE + col] = (bf16)p;
        d[2 * EE + col] = (bf16)(cv * p);
        d[3 * EE + col] = (bf16)(cv * qv);
      }
    }
  }
}

// ---------------------------------------------------------------------------
// launcher — 7 kernels
// ---------------------------------------------------------------------------
extern "C" void kernel_launch(void* const* d_in, const int* in_sizes, int n_in,
                              void* d_out, int out_size, void* d_ws, size_t ws_size,
                              hipStream_t stream) {
  const float* ctx = (const float*)d_in[0];
  const float* qst = (const float*)d_in[1];
  const float* mask = (const float*)d_in[2];
  const float* wq = (const float*)d_in[3];
  const float* wc = (const float*)d_in[4];
  const float* wmul = (const float*)d_in[5];
  const float* W1 = (const float*)d_in[6];
  const float* b1 = (const float*)d_in[7];
  const float* W2 = (const float*)d_in[8];
  const float* b2 = (const float*)d_in[9];
  float* out = (float*)d_out;
  char* ws = (char*)d_ws;

  bf16* att = (bf16*)(ws);                  // 33554432
  bf16* hbuf = (bf16*)(ws + 33554432);      // 16777216
  bf16* W1T = (bf16*)(ws + 50331648);       // 4194304
  bf16* W2T = (bf16*)(ws + 54525952);       // 4194304
  bf16* qT = (bf16*)(ws + 58720256);        // 1048576
  float* sim = (float*)(ws + 59768832);     // 4194304
  bf16* P = (bf16*)(ws + 63963136);         // 2097152
  float* smax = (float*)(ws + 66060288);    // 32768
  float* q2c = (float*)(ws + 66093056);     // 16384

  prep_kernel<<<4608, 256, 0, stream>>>(W1, W2, qst, W1T, W2T, qT);
  sim_kernel<<<dim3(16, BB), 256, 0, stream>>>(ctx, qst, wq, wc, wmul, sim);
  softmax_q_kernel<<<2048, 256, 0, stream>>>(sim, P, smax);
  q2c_kernel<<<64, 256, 0, stream>>>(ctx, smax, q2c);
  c2q_att_kernel<<<dim3(32, BB), 256, 0, stream>>>(P, qT, ctx, q2c, att);
  gemm_bt_kernel<64, 1, 0, 1, 1><<<dim3(1024, 1), 256, 0, stream>>>(
      att, W1T, b1, mask, hbuf, 8192, 1024, 2048, 0, 0, 0);
  gemm_bt_kernel<128, 0, 1, 1, 1><<<dim3(1024, 1), 256, 0, stream>>>(
      hbuf, W2T, b2, mask, out, 8192, 2048, 1024, 0, 0, 0);
}

// Round 3
// 250.205 us; speedup vs baseline: 1.2421x; 1.2421x over previous
//
#include <hip/hip_runtime.h>

typedef __bf16 bf16;
typedef __bf16 bf16x4 __attribute__((ext_vector_type(4)));
typedef __bf16 bf16x8 __attribute__((ext_vector_type(8)));
typedef float f32x4 __attribute__((ext_vector_type(4)));

#define AS1 __attribute__((address_space(1)))
#define AS3 __attribute__((address_space(3)))

__device__ __forceinline__ void async_copy16(const void* g, void* l) {
  // global -> LDS direct, 16B/lane; LDS dest = wave-uniform base + lane*16.
  __builtin_amdgcn_global_load_lds((const AS1 void*)g, (AS3 void*)l, 16, 0, 0);
}

#define BB 8
#define CC 1024
#define QQ 128
#define EE 512
#define HH 1024
#define FOURE 2048

// ---------------------------------------------------------------------------
// prep: three f32->bf16 transposes in one launch.
// ---------------------------------------------------------------------------
__global__ __launch_bounds__(256) void prep_kernel(
    const float* __restrict__ W1, const float* __restrict__ W2,
    const float* __restrict__ qst, bf16* __restrict__ W1T,
    bf16* __restrict__ W2T, bf16* __restrict__ qT) {
  __shared__ float tile[32][33];
  int bx = blockIdx.x;
  const float* src;
  bf16* dst;
  int R, C, idx;
  if (bx < 2048) {
    src = W1; dst = W1T; R = 2048; C = 1024; idx = bx;
  } else if (bx < 4096) {
    src = W2; dst = W2T; R = 1024; C = 2048; idx = bx - 2048;
  } else {
    int i = bx - 4096;
    int b = i >> 6; idx = i & 63;
    src = qst + (size_t)b * QQ * EE; dst = qT + (size_t)b * EE * QQ;
    R = 128; C = 512;
  }
  int ctiles = C >> 5;
  int by = idx / ctiles, cx = idx % ctiles;
  int tx = threadIdx.x & 31, ty = threadIdx.x >> 5;
#pragma unroll
  for (int rr = 0; rr < 4; ++rr)
    tile[ty + rr * 8][tx] = src[(size_t)(by * 32 + ty + rr * 8) * C + cx * 32 + tx];
  __syncthreads();
#pragma unroll
  for (int rr = 0; rr < 4; ++rr)
    dst[(size_t)(cx * 32 + ty + rr * 8) * R + by * 32 + tx] = (bf16)tile[tx][ty + rr * 8];
}

// ---------------------------------------------------------------------------
// sim: sim[b,c,q] = sum_e ctx*(qst*wmul) + qw[q] + cw[c], split-bf16 (3 MFMA).
// Fused rowdot. Tile 64x128, BK=32, grid 16x8.
// ---------------------------------------------------------------------------
__global__ __launch_bounds__(256) void sim_kernel(
    const float* __restrict__ ctx, const float* __restrict__ qst,
    const float* __restrict__ wq, const float* __restrict__ wc,
    const float* __restrict__ wmul, float* __restrict__ sim) {
  int b = blockIdx.y;
  int m0 = blockIdx.x * 64;
  __shared__ bf16 Ah[64 * 32], Al[64 * 32], Bh[128 * 32], Bl[128 * 32];
  __shared__ float wq_s[EE], wc_s[EE], wm_s[EE];
  __shared__ float cw_s[64], qw_s[128];
  int t = threadIdx.x;
  for (int i = t; i < EE; i += 256) {
    wq_s[i] = wq[i]; wc_s[i] = wc[i]; wm_s[i] = wmul[i];
  }
  __syncthreads();
  int wv = t >> 6, ln = t & 63, wm = wv >> 1, wn = wv & 1;
  f32x4 acc[2][4] = {};
  const float* Ag = ctx + ((size_t)b * CC + m0) * EE;
  const float* Bg = qst + (size_t)b * QQ * EE;
  int arow = t >> 2, acq = t & 3;
  int brow = t >> 1, bcq0 = (t & 1) * 2;
  float cwp = 0.f, qwp = 0.f;
  for (int k0 = 0; k0 < EE; k0 += 32) {
    {
      const float4* s4 = (const float4*)(Ag + (size_t)arow * EE + k0 + acq * 8);
      float4 v0 = s4[0], v1 = s4[1];
      float vals[8] = {v0.x, v0.y, v0.z, v0.w, v1.x, v1.y, v1.z, v1.w};
      bf16x8 h, l;
#pragma unroll
      for (int i = 0; i < 8; ++i) {
        cwp += vals[i] * wc_s[k0 + acq * 8 + i];
        bf16 hh = (bf16)vals[i];
        h[i] = hh; l[i] = (bf16)(vals[i] - (float)hh);
      }
      int sl = (acq ^ ((arow >> 1) & 3)) * 8;
      *(bf16x8*)&Ah[arow * 32 + sl] = h;
      *(bf16x8*)&Al[arow * 32 + sl] = l;
    }
#pragma unroll
    for (int cc = 0; cc < 2; ++cc) {
      int cq = bcq0 + cc;
      const float4* s4 = (const float4*)(Bg + (size_t)brow * EE + k0 + cq * 8);
      float4 v0 = s4[0], v1 = s4[1];
      float vals[8] = {v0.x, v0.y, v0.z, v0.w, v1.x, v1.y, v1.z, v1.w};
      bf16x8 h, l;
#pragma unroll
      for (int i = 0; i < 8; ++i) {
        qwp += vals[i] * wq_s[k0 + cq * 8 + i];
        float sv = vals[i] * wm_s[k0 + cq * 8 + i];
        bf16 hh = (bf16)sv;
        h[i] = hh; l[i] = (bf16)(sv - (float)hh);
      }
      int sl = (cq ^ ((brow >> 1) & 3)) * 8;
      *(bf16x8*)&Bh[brow * 32 + sl] = h;
      *(bf16x8*)&Bl[brow * 32 + sl] = l;
    }
    __syncthreads();
    int rl = ln & 15, kq = ln >> 4;
    bf16x8 ah[2], al[2], bh[4], bl[4];
#pragma unroll
    for (int i = 0; i < 2; ++i) {
      int r = wm * 32 + i * 16 + rl;
      int sl = (kq ^ ((r >> 1) & 3)) * 8;
      ah[i] = *(const bf16x8*)&Ah[r * 32 + sl];
      al[i] = *(const bf16x8*)&Al[r * 32 + sl];
    }
#pragma unroll
    for (int j = 0; j < 4; ++j) {
      int r = wn * 64 + j * 16 + rl;
      int sl = (kq ^ ((r >> 1) & 3)) * 8;
      bh[j] = *(const bf16x8*)&Bh[r * 32 + sl];
      bl[j] = *(const bf16x8*)&Bl[r * 32 + sl];
    }
#pragma unroll
    for (int i = 0; i < 2; ++i)
#pragma unroll
      for (int j = 0; j < 4; ++j) {
        acc[i][j] = __builtin_amdgcn_mfma_f32_16x16x32_bf16(ah[i], bh[j], acc[i][j], 0, 0, 0);
        acc[i][j] = __builtin_amdgcn_mfma_f32_16x16x32_bf16(ah[i], bl[j], acc[i][j], 0, 0, 0);
        acc[i][j] = __builtin_amdgcn_mfma_f32_16x16x32_bf16(al[i], bh[j], acc[i][j], 0, 0, 0);
      }
    __syncthreads();
  }
  float s = cwp;
  s += __shfl_xor(s, 1); s += __shfl_xor(s, 2);
  if ((t & 3) == 0) cw_s[arow] = s;
  float s2 = qwp;
  s2 += __shfl_xor(s2, 1);
  if (!(t & 1)) qw_s[brow] = s2;
  __syncthreads();
  float* simb = sim + ((size_t)b * CC + m0) * QQ;
#pragma unroll
  for (int j = 0; j < 4; ++j) {
    int col = wn * 64 + j * 16 + (ln & 15);
    float qv = qw_s[col];
#pragma unroll
    for (int i = 0; i < 2; ++i) {
      int rbase = wm * 32 + i * 16 + ((ln >> 4) << 2);
#pragma unroll
      for (int r = 0; r < 4; ++r) {
        int rowl = rbase + r;
        simb[(size_t)rowl * QQ + col] = acc[i][j][r] + qv + cw_s[rowl];
      }
    }
  }
}

// ---------------------------------------------------------------------------
// softmax over q (128) per (b,c) row; one wave/row. P bf16 + row max.
// ---------------------------------------------------------------------------
__global__ __launch_bounds__(256) void softmax_q_kernel(
    const float* __restrict__ sim, bf16* __restrict__ P, float* __restrict__ smax) {
  int row = blockIdx.x * 4 + (threadIdx.x >> 6);
  int ln = threadIdx.x & 63;
  const float* s = sim + (size_t)row * QQ;
  float v0 = s[ln], v1 = s[64 + ln];
  float mx = fmaxf(v0, v1);
#pragma unroll
  for (int off = 32; off; off >>= 1) mx = fmaxf(mx, __shfl_xor(mx, off));
  float e0 = __expf(v0 - mx), e1 = __expf(v1 - mx);
  float sm = e0 + e1;
#pragma unroll
  for (int off = 32; off; off >>= 1) sm += __shfl_xor(sm, off);
  float inv = 1.0f / sm;
  P[(size_t)row * QQ + ln] = (bf16)(e0 * inv);
  P[(size_t)row * QQ + 64 + ln] = (bf16)(e1 * inv);
  if (ln == 0) smax[row] = mx;
}

// ---------------------------------------------------------------------------
// softmax over c (1024) per b -> cwt. 8 blocks.
// ---------------------------------------------------------------------------
__global__ __launch_bounds__(256) void softmax_c_kernel(
    const float* __restrict__ smax, float* __restrict__ cwt) {
  int b = blockIdx.x, t = threadIdx.x;
  __shared__ float red[256];
  float v[4];
  float mx = -3.4e38f;
#pragma unroll
  for (int i = 0; i < 4; ++i) {
    v[i] = smax[b * CC + i * 256 + t];
    mx = fmaxf(mx, v[i]);
  }
  red[t] = mx;
  __syncthreads();
  for (int s = 128; s > 0; s >>= 1) {
    if (t < s) red[t] = fmaxf(red[t], red[t + s]);
    __syncthreads();
  }
  mx = red[0];
  __syncthreads();
  float ex[4], sm = 0.f;
#pragma unroll
  for (int i = 0; i < 4; ++i) { ex[i] = __expf(v[i] - mx); sm += ex[i]; }
  red[t] = sm;
  __syncthreads();
  for (int s = 128; s > 0; s >>= 1) {
    if (t < s) red[t] += red[t + s];
    __syncthreads();
  }
  float inv = 1.0f / red[0];
#pragma unroll
  for (int i = 0; i < 4; ++i) cwt[b * CC + i * 256 + t] = ex[i] * inv;
}

// ---------------------------------------------------------------------------
// q2c partial: grid 256 = 8b x 32 chunks of 32 c-rows. float2 loads,
// atomicAdd into pre-zeroed q2c[b,e]. 16.7 MB total read ~ BW-bound.
// ---------------------------------------------------------------------------
__global__ __launch_bounds__(256) void q2c_kernel(
    const float* __restrict__ ctx, const float* __restrict__ cwt,
    float* __restrict__ q2c) {
  int b = blockIdx.x >> 5, ch = blockIdx.x & 31;
  int t = threadIdx.x;
  int e = t * 2;
  const float* cb = ctx + ((size_t)b * CC + ch * 32) * EE;
  const float* wb = cwt + b * CC + ch * 32;
  float a0 = 0.f, a1 = 0.f;
#pragma unroll 8
  for (int r = 0; r < 32; ++r) {
    float2 v = *(const float2*)&cb[(size_t)r * EE + e];
    float w = wb[r];
    a0 += w * v.x;
    a1 += w * v.y;
  }
  atomicAdd(&q2c[b * EE + e], a0);
  atomicAdd(&q2c[b * EE + e + 1], a1);
}

// ---------------------------------------------------------------------------
// Unified bf16 GEMM: C = A(MxK) @ Bt(NxK)^T. Tile MT x 128, BK=64,
// global_load_lds 16B staging with XOR chunk-swizzle, 16x16x32 bf16 MFMA.
// ---------------------------------------------------------------------------
template <int MT, int OUT_BF16, int RELU, int HAS_BIAS, int HAS_MASK>
__global__ __launch_bounds__(256) void gemm_bt_kernel(
    const bf16* __restrict__ A, const bf16* __restrict__ Bt,
    const float* __restrict__ bias, const float* __restrict__ mask,
    void* __restrict__ Cout, int M, int N, int K, long sA, long sB, long sC) {
  int b = blockIdx.y;
  A += (size_t)b * sA;
  Bt += (size_t)b * sB;
  int ntiles = N >> 7;
  int mt = blockIdx.x / ntiles, ntb = blockIdx.x % ntiles;
  int m0 = mt * MT, n0 = ntb << 7;
  __shared__ bf16 As[MT * 64];
  __shared__ bf16 Bs[128 * 64];
  int t = threadIdx.x, wv = t >> 6, ln = t & 63;
  int wm = wv >> 1, wn = wv & 1;
  constexpr int MI = MT / 32;
  f32x4 acc[MI][4] = {};
  for (int k0 = 0; k0 < K; k0 += 64) {
#pragma unroll
    for (int r = 0; r < MT / 32; ++r) {
      int fb = (r * 4 + wv) * 1024 + ln * 16;
      int row = fb >> 7;
      int q = ((fb >> 4) & 7) ^ (row & 7);
      async_copy16(A + (size_t)(m0 + row) * K + k0 + q * 8,
                   (char*)As + (r * 4 + wv) * 1024);
    }
#pragma unroll
    for (int r = 0; r < 4; ++r) {
      int fb = (r * 4 + wv) * 1024 + ln * 16;
      int row = fb >> 7;
      int q = ((fb >> 4) & 7) ^ (row & 7);
      async_copy16(Bt + (size_t)(n0 + row) * K + k0 + q * 8,
                   (char*)Bs + (r * 4 + wv) * 1024);
    }
    __syncthreads();
    int rl = ln & 15, kq = ln >> 4;
#pragma unroll
    for (int ks = 0; ks < 2; ++ks) {
      int c = ks * 4 + kq;
      bf16x8 af[MI], bfr[4];
#pragma unroll
      for (int i = 0; i < MI; ++i) {
        int row = wm * (MT / 2) + i * 16 + rl;
        af[i] = *(const bf16x8*)&As[row * 64 + ((c ^ (row & 7)) * 8)];
      }
#pragma unroll
      for (int j = 0; j < 4; ++j) {
        int row = wn * 64 + j * 16 + rl;
        bfr[j] = *(const bf16x8*)&Bs[row * 64 + ((c ^ (row & 7)) * 8)];
      }
#pragma unroll
      for (int i = 0; i < MI; ++i)
#pragma unroll
        for (int j = 0; j < 4; ++j)
          acc[i][j] = __builtin_amdgcn_mfma_f32_16x16x32_bf16(af[i], bfr[j], acc[i][j], 0, 0, 0);
    }
    __syncthreads();
  }
  size_t outbase = (size_t)b * sC;
#pragma unroll
  for (int j = 0; j < 4; ++j) {
    int col = n0 + wn * 64 + j * 16 + (ln & 15);
    float bv = HAS_BIAS ? bias[col] : 0.f;
#pragma unroll
    for (int i = 0; i < MI; ++i) {
      int rbase = m0 + wm * (MT / 2) + i * 16 + ((ln >> 4) << 2);
#pragma unroll
      for (int r = 0; r < 4; ++r) {
        int row = rbase + r;
        float v = acc[i][j][r] + bv;
        if (HAS_MASK) v *= mask[row];
        if (RELU) v = fmaxf(v, 0.f);
        if (OUT_BF16)
          ((bf16*)Cout)[outbase + (size_t)row * N + col] = (bf16)v;
        else
          ((float*)Cout)[outbase + (size_t)row * N + col] = v;
      }
    }
  }
}

// ---------------------------------------------------------------------------
// attended build (vectorized): att = [ctx | c2q | ctx*c2q | ctx*q2c[b]]
// ---------------------------------------------------------------------------
__global__ __launch_bounds__(256) void attbuild_kernel(
    const float* __restrict__ ctx, const bf16* __restrict__ c2q,
    const float* __restrict__ q2c, bf16* __restrict__ att) {
  int idx = blockIdx.x * 256 + threadIdx.x;
  int row = idx >> 7;
  int e = (idx & 127) * 4;
  int b = row >> 10;
  float4 cv = *(const float4*)&ctx[(size_t)row * EE + e];
  bf16x4 qv = *(const bf16x4*)&c2q[(size_t)row * EE + e];
  float4 gv = *(const float4*)&q2c[b * EE + e];
  bf16* dst = att + (size_t)row * FOURE;
  bf16x4 o0, o2, o3;
  o0[0] = (bf16)cv.x; o0[1] = (bf16)cv.y; o0[2] = (bf16)cv.z; o0[3] = (bf16)cv.w;
  o2[0] = (bf16)(cv.x * (float)qv[0]); o2[1] = (bf16)(cv.y * (float)qv[1]);
  o2[2] = (bf16)(cv.z * (float)qv[2]); o2[3] = (bf16)(cv.w * (float)qv[3]);
  o3[0] = (bf16)(cv.x * gv.x); o3[1] = (bf16)(cv.y * gv.y);
  o3[2] = (bf16)(cv.z * gv.z); o3[3] = (bf16)(cv.w * gv.w);
  *(bf16x4*)&dst[e] = o0;
  *(bf16x4*)&dst[512 + e] = qv;
  *(bf16x4*)&dst[1024 + e] = o2;
  *(bf16x4*)&dst[1536 + e] = o3;
}

// ---------------------------------------------------------------------------
// launcher
// ---------------------------------------------------------------------------
extern "C" void kernel_launch(void* const* d_in, const int* in_sizes, int n_in,
                              void* d_out, int out_size, void* d_ws, size_t ws_size,
                              hipStream_t stream) {
  const float* ctx = (const float*)d_in[0];
  const float* qst = (const float*)d_in[1];
  const float* mask = (const float*)d_in[2];
  const float* wq = (const float*)d_in[3];
  const float* wc = (const float*)d_in[4];
  const float* wmul = (const float*)d_in[5];
  const float* W1 = (const float*)d_in[6];
  const float* b1 = (const float*)d_in[7];
  const float* W2 = (const float*)d_in[8];
  const float* b2 = (const float*)d_in[9];
  float* out = (float*)d_out;
  char* ws = (char*)d_ws;

  bf16* att = (bf16*)(ws);                  // 33554432
  bf16* hbuf = (bf16*)(ws + 33554432);      // 16777216
  bf16* W1T = (bf16*)(ws + 50331648);       // 4194304
  bf16* W2T = (bf16*)(ws + 54525952);       // 4194304
  bf16* qT = (bf16*)(ws + 58720256);        // 1048576
  float* sim = (float*)(ws + 59768832);     // 4194304
  bf16* P = (bf16*)(ws + 63963136);         // 2097152
  bf16* c2q = (bf16*)(ws + 66060288);       // 8388608
  float* smax = (float*)(ws + 74448896);    // 32768
  float* cwt = (float*)(ws + 74481664);     // 32768
  float* q2c = (float*)(ws + 74514432);     // 16384

  prep_kernel<<<4608, 256, 0, stream>>>(W1, W2, qst, W1T, W2T, qT);
  sim_kernel<<<dim3(16, BB), 256, 0, stream>>>(ctx, qst, wq, wc, wmul, sim);
  softmax_q_kernel<<<2048, 256, 0, stream>>>(sim, P, smax);
  softmax_c_kernel<<<BB, 256, 0, stream>>>(smax, cwt);
  hipMemsetAsync(q2c, 0, BB * EE * sizeof(float), stream);
  q2c_kernel<<<256, 256, 0, stream>>>(ctx, cwt, q2c);
  gemm_bt_kernel<128, 1, 0, 0, 0><<<dim3(32, BB), 256, 0, stream>>>(
      P, qT, nullptr, nullptr, c2q, 1024, 512, 128,
      (long)CC * QQ, (long)EE * QQ, (long)CC * EE);
  attbuild_kernel<<<4096, 256, 0, stream>>>(ctx, c2q, q2c, att);
  gemm_bt_kernel<64, 1, 0, 1, 1><<<dim3(1024, 1), 256, 0, stream>>>(
      att, W1T, b1, mask, hbuf, 8192, 1024, 2048, 0, 0, 0);
  gemm_bt_kernel<128, 0, 1, 1, 1><<<dim3(1024, 1), 256, 0, stream>>>(
      hbuf, W2T, b2, mask, out, 8192, 2048, 1024, 0, 0, 0);
}

// Round 4
// 242.085 us; speedup vs baseline: 1.2837x; 1.0335x over previous
//
#include <hip/hip_runtime.h>

typedef __bf16 bf16;
typedef __bf16 bf16x4 __attribute__((ext_vector_type(4)));
typedef __bf16 bf16x8 __attribute__((ext_vector_type(8)));
typedef float f32x4 __attribute__((ext_vector_type(4)));
typedef float f32x16 __attribute__((ext_vector_type(16)));

#define AS1 __attribute__((address_space(1)))
#define AS3 __attribute__((address_space(3)))

__device__ __forceinline__ void async_copy16(const void* g, void* l) {
  // global -> LDS direct, 16B/lane; LDS dest = wave-uniform base + lane*16.
  __builtin_amdgcn_global_load_lds((const AS1 void*)g, (AS3 void*)l, 16, 0, 0);
}

#define BB 8
#define CC 1024
#define QQ 128
#define EE 512
#define HH 1024
#define FOURE 2048

// ---------------------------------------------------------------------------
// prep:
//  bx [0,2048):    W1 (2048x1024) -> W1T
//  bx [2048,4096): W2 (1024x2048) -> W2T
//  bx [4096,4608): question per-batch transpose -> qT
//  bx [4608,5120): qm = question*wmul -> bf16 hi/lo (qmh/qml) + qw row-dots
// ---------------------------------------------------------------------------
__global__ __launch_bounds__(256) void prep_kernel(
    const float* __restrict__ W1, const float* __restrict__ W2,
    const float* __restrict__ qst, const float* __restrict__ wmul,
    const float* __restrict__ wqv, bf16* __restrict__ W1T,
    bf16* __restrict__ W2T, bf16* __restrict__ qT,
    bf16* __restrict__ qmh, bf16* __restrict__ qml, float* __restrict__ qw) {
  __shared__ float tile[32][33];
  __shared__ float r4[4];
  int bx = blockIdx.x;
  int t = threadIdx.x;
  if (bx >= 4608) {
    // qm + qw path: 2 question rows per block
    int i = bx - 4608;
    int half = t >> 7, tr = t & 127;
    int rowg = i * 2 + half;  // 0..1023 over (b,q)
    const float* qrow = qst + (size_t)rowg * EE;
    float4 qv = *(const float4*)&qrow[tr * 4];
    float4 wm4 = *(const float4*)&wmul[tr * 4];
    float4 wq4 = *(const float4*)&wqv[tr * 4];
    float m[4] = {qv.x * wm4.x, qv.y * wm4.y, qv.z * wm4.z, qv.w * wm4.w};
    bf16x4 h, l;
#pragma unroll
    for (int k = 0; k < 4; ++k) {
      bf16 hh = (bf16)m[k];
      h[k] = hh; l[k] = (bf16)(m[k] - (float)hh);
    }
    *(bf16x4*)&qmh[(size_t)rowg * EE + tr * 4] = h;
    *(bf16x4*)&qml[(size_t)rowg * EE + tr * 4] = l;
    float s = qv.x * wq4.x + qv.y * wq4.y + qv.z * wq4.z + qv.w * wq4.w;
#pragma unroll
    for (int off = 32; off; off >>= 1) s += __shfl_xor(s, off);
    if ((t & 63) == 0) r4[t >> 6] = s;
    __syncthreads();
    if (tr == 0) qw[rowg] = r4[half * 2] + r4[half * 2 + 1];
    return;
  }
  const float* src;
  bf16* dst;
  int R, C, idx;
  if (bx < 2048) {
    src = W1; dst = W1T; R = 2048; C = 1024; idx = bx;
  } else if (bx < 4096) {
    src = W2; dst = W2T; R = 1024; C = 2048; idx = bx - 2048;
  } else {
    int i = bx - 4096;
    int b = i >> 6; idx = i & 63;
    src = qst + (size_t)b * QQ * EE; dst = qT + (size_t)b * EE * QQ;
    R = 128; C = 512;
  }
  int ctiles = C >> 5;
  int by = idx / ctiles, cx = idx % ctiles;
  int tx = t & 31, ty = t >> 5;
#pragma unroll
  for (int rr = 0; rr < 4; ++rr)
    tile[ty + rr * 8][tx] = src[(size_t)(by * 32 + ty + rr * 8) * C + cx * 32 + tx];
  __syncthreads();
#pragma unroll
  for (int rr = 0; rr < 4; ++rr)
    dst[(size_t)(cx * 32 + ty + rr * 8) * R + by * 32 + tx] = (bf16)tile[tx][ty + rr * 8];
}

// ---------------------------------------------------------------------------
// sim + fused softmax_q: computes sim[b,c,q] (split-bf16 3-MFMA, fp32-grade),
// adds qw[q]/cw[c] (cw fused from A staging), then softmax over q in-LDS.
// Writes P (bf16) and smax (row max incl. cw). Tile 64x128, grid 16x8.
// B (qm hi/lo) staged via global_load_lds from prep's precompute.
// ---------------------------------------------------------------------------
__global__ __launch_bounds__(256) void sim_kernel(
    const float* __restrict__ ctx, const bf16* __restrict__ qmh,
    const bf16* __restrict__ qml, const float* __restrict__ wc,
    const float* __restrict__ qw, bf16* __restrict__ P,
    float* __restrict__ smax) {
  int b = blockIdx.y;
  int m0 = blockIdx.x * 64;
  __shared__ bf16 Ah[64 * 32], Al[64 * 32], Bh[128 * 32], Bl[128 * 32];
  __shared__ float wc_s[EE];
  __shared__ float qw_s[QQ];
  __shared__ float cw_s[64];
  __shared__ float sim_s[64][132];
  int t = threadIdx.x;
  for (int i = t; i < EE; i += 256) wc_s[i] = wc[i];
  if (t < QQ) qw_s[t] = qw[b * QQ + t];
  __syncthreads();
  int wv = t >> 6, ln = t & 63, wm = wv >> 1, wn = wv & 1;
  f32x4 acc[2][4] = {};
  const float* Ag = ctx + ((size_t)b * CC + m0) * EE;
  const bf16* Bhg = qmh + (size_t)b * QQ * EE;
  const bf16* Blg = qml + (size_t)b * QQ * EE;
  int arow = t >> 2, acq = t & 3;
  float cwp = 0.f;
  for (int k0 = 0; k0 < EE; k0 += 32) {
    {  // A stage: f32 load, hi/lo repack, cw accumulation
      const float4* s4 = (const float4*)(Ag + (size_t)arow * EE + k0 + acq * 8);
      float4 v0 = s4[0], v1 = s4[1];
      float vals[8] = {v0.x, v0.y, v0.z, v0.w, v1.x, v1.y, v1.z, v1.w};
      bf16x8 h, l;
#pragma unroll
      for (int i = 0; i < 8; ++i) {
        cwp += vals[i] * wc_s[k0 + acq * 8 + i];
        bf16 hh = (bf16)vals[i];
        h[i] = hh; l[i] = (bf16)(vals[i] - (float)hh);
      }
      int sl = (acq ^ ((arow >> 1) & 3)) * 8;
      *(bf16x8*)&Ah[arow * 32 + sl] = h;
      *(bf16x8*)&Al[arow * 32 + sl] = l;
    }
#pragma unroll
    for (int r = 0; r < 2; ++r) {  // B stage: async from precomputed qm hi/lo
      int fb = (r * 4 + wv) * 1024 + ln * 16;
      int row = fb >> 6;
      int cq = ((fb >> 4) & 3) ^ ((row >> 1) & 3);
      async_copy16(Bhg + (size_t)row * EE + k0 + cq * 8, (char*)Bh + fb);
      async_copy16(Blg + (size_t)row * EE + k0 + cq * 8, (char*)Bl + fb);
    }
    __syncthreads();
    int rl = ln & 15, kq = ln >> 4;
    bf16x8 ah[2], al[2], bh[4], bl[4];
#pragma unroll
    for (int i = 0; i < 2; ++i) {
      int r = wm * 32 + i * 16 + rl;
      int sl = (kq ^ ((r >> 1) & 3)) * 8;
      ah[i] = *(const bf16x8*)&Ah[r * 32 + sl];
      al[i] = *(const bf16x8*)&Al[r * 32 + sl];
    }
#pragma unroll
    for (int j = 0; j < 4; ++j) {
      int r = wn * 64 + j * 16 + rl;
      int sl = (kq ^ ((r >> 1) & 3)) * 8;
      bh[j] = *(const bf16x8*)&Bh[r * 32 + sl];
      bl[j] = *(const bf16x8*)&Bl[r * 32 + sl];
    }
#pragma unroll
    for (int i = 0; i < 2; ++i)
#pragma unroll
      for (int j = 0; j < 4; ++j) {
        acc[i][j] = __builtin_amdgcn_mfma_f32_16x16x32_bf16(ah[i], bh[j], acc[i][j], 0, 0, 0);
        acc[i][j] = __builtin_amdgcn_mfma_f32_16x16x32_bf16(ah[i], bl[j], acc[i][j], 0, 0, 0);
        acc[i][j] = __builtin_amdgcn_mfma_f32_16x16x32_bf16(al[i], bh[j], acc[i][j], 0, 0, 0);
      }
    __syncthreads();
  }
  // cw reduce (4 lanes/row)
  float s = cwp;
  s += __shfl_xor(s, 1); s += __shfl_xor(s, 2);
  if ((t & 3) == 0) cw_s[arow] = s;
  // spill sim (+qw) to LDS
#pragma unroll
  for (int j = 0; j < 4; ++j) {
    int col = wn * 64 + j * 16 + (ln & 15);
    float qv = qw_s[col];
#pragma unroll
    for (int i = 0; i < 2; ++i) {
      int rbase = wm * 32 + i * 16 + ((ln >> 4) << 2);
#pragma unroll
      for (int r = 0; r < 4; ++r)
        sim_s[rbase + r][col] = acc[i][j][r] + qv;
    }
  }
  __syncthreads();
  // softmax over q: 4 threads/row, strided cols (conflict-free)
  int row = t >> 2, cb = t & 3;
  float v[32];
  float mx = -3.4e38f;
#pragma unroll
  for (int k = 0; k < 32; ++k) {
    v[k] = sim_s[row][cb + 4 * k];
    mx = fmaxf(mx, v[k]);
  }
  mx = fmaxf(mx, __shfl_xor(mx, 1));
  mx = fmaxf(mx, __shfl_xor(mx, 2));
  float sm = 0.f;
#pragma unroll
  for (int k = 0; k < 32; ++k) { v[k] = __expf(v[k] - mx); sm += v[k]; }
  sm += __shfl_xor(sm, 1);
  sm += __shfl_xor(sm, 2);
  float inv = 1.0f / sm;
  bf16* Pr = P + (size_t)(b * CC + m0 + row) * QQ;
#pragma unroll
  for (int k = 0; k < 32; ++k) Pr[cb + 4 * k] = (bf16)(v[k] * inv);
  if (cb == 0) smax[b * CC + m0 + row] = mx + cw_s[row];
}

// ---------------------------------------------------------------------------
// q2c with fused (redundant per-block) softmax over c:
// q2c[b,e] += sum over this block's 32 c-rows of softmax_c(smax)[c]*ctx[b,c,e]
// Grid 256 = 8b x 32 chunks. atomicAdd into pre-zeroed q2c.
// ---------------------------------------------------------------------------
__global__ __launch_bounds__(256) void q2c_kernel(
    const float* __restrict__ ctx, const float* __restrict__ smax,
    float* __restrict__ q2c) {
  int b = blockIdx.x >> 5, ch = blockIdx.x & 31;
  int t = threadIdx.x;
  __shared__ float red[256];
  __shared__ float w_s[32];
  float v[4];
  float mx = -3.4e38f;
#pragma unroll
  for (int i = 0; i < 4; ++i) {
    v[i] = smax[b * CC + i * 256 + t];
    mx = fmaxf(mx, v[i]);
  }
  red[t] = mx;
  __syncthreads();
  for (int s = 128; s > 0; s >>= 1) {
    if (t < s) red[t] = fmaxf(red[t], red[t + s]);
    __syncthreads();
  }
  mx = red[0];
  __syncthreads();
  float sm = 0.f;
#pragma unroll
  for (int i = 0; i < 4; ++i) sm += __expf(v[i] - mx);
  red[t] = sm;
  __syncthreads();
  for (int s = 128; s > 0; s >>= 1) {
    if (t < s) red[t] += red[t + s];
    __syncthreads();
  }
  float inv = 1.0f / red[0];
  if (t < 32) w_s[t] = __expf(smax[b * CC + ch * 32 + t] - mx) * inv;
  __syncthreads();
  int e = t * 2;
  const float* cb = ctx + ((size_t)b * CC + ch * 32) * EE;
  float a0 = 0.f, a1 = 0.f;
#pragma unroll 8
  for (int r = 0; r < 32; ++r) {
    float2 vv = *(const float2*)&cb[(size_t)r * EE + e];
    float w = w_s[r];
    a0 += w * vv.x;
    a1 += w * vv.y;
  }
  atomicAdd(&q2c[b * EE + e], a0);
  atomicAdd(&q2c[b * EE + e + 1], a1);
}

// ---------------------------------------------------------------------------
// Unified bf16 GEMM, now 32x32x16 MFMA: C = A(MxK) @ Bt(NxK)^T.
// Tile MT x 128 (wave-tile 64x64 = 2x2 of 32x32), BK=64, async staging with
// XOR chunk swizzle. A/B frag: m(or n)=lane&31, k=(lane>>5)*8+j.
// C/D: col=lane&31, row=(reg&3)+8*(reg>>2)+4*(lane>>5)  [m74/m101].
// ---------------------------------------------------------------------------
template <int MT, int OUT_BF16, int RELU, int HAS_BIAS, int HAS_MASK>
__global__ __launch_bounds__(256) void gemm_bt_kernel(
    const bf16* __restrict__ A, const bf16* __restrict__ Bt,
    const float* __restrict__ bias, const float* __restrict__ mask,
    void* __restrict__ Cout, int M, int N, int K, long sA, long sB, long sC) {
  int b = blockIdx.y;
  A += (size_t)b * sA;
  Bt += (size_t)b * sB;
  int ntiles = N >> 7;
  int mt = blockIdx.x / ntiles, ntb = blockIdx.x % ntiles;
  int m0 = mt * MT, n0 = ntb << 7;
  __shared__ bf16 As[MT * 64];
  __shared__ bf16 Bs[128 * 64];
  int t = threadIdx.x, wv = t >> 6, ln = t & 63;
  int wm = wv >> 1, wn = wv & 1;
  constexpr int MI = MT / 64;
  f32x16 acc[MI][2] = {};
  for (int k0 = 0; k0 < K; k0 += 64) {
#pragma unroll
    for (int r = 0; r < MT / 32; ++r) {
      int fb = (r * 4 + wv) * 1024 + ln * 16;
      int row = fb >> 7;
      int q = ((fb >> 4) & 7) ^ (row & 7);
      async_copy16(A + (size_t)(m0 + row) * K + k0 + q * 8,
                   (char*)As + fb);
    }
#pragma unroll
    for (int r = 0; r < 4; ++r) {
      int fb = (r * 4 + wv) * 1024 + ln * 16;
      int row = fb >> 7;
      int q = ((fb >> 4) & 7) ^ (row & 7);
      async_copy16(Bt + (size_t)(n0 + row) * K + k0 + q * 8,
                   (char*)Bs + fb);
    }
    __syncthreads();
    int rl = ln & 31, kh = ln >> 5;
#pragma unroll
    for (int s = 0; s < 4; ++s) {
      int c = s * 2 + kh;  // 8-elem chunk index within the 64-K tile
      bf16x8 af[MI], bfr[2];
#pragma unroll
      for (int i = 0; i < MI; ++i) {
        int row = wm * (MT / 2) + i * 32 + rl;
        af[i] = *(const bf16x8*)&As[row * 64 + ((c ^ (row & 7)) * 8)];
      }
#pragma unroll
      for (int j = 0; j < 2; ++j) {
        int row = wn * 64 + j * 32 + rl;
        bfr[j] = *(const bf16x8*)&Bs[row * 64 + ((c ^ (row & 7)) * 8)];
      }
#pragma unroll
      for (int i = 0; i < MI; ++i)
#pragma unroll
        for (int j = 0; j < 2; ++j)
          acc[i][j] = __builtin_amdgcn_mfma_f32_32x32x16_bf16(af[i], bfr[j], acc[i][j], 0, 0, 0);
    }
    __syncthreads();
  }
  size_t outbase = (size_t)b * sC;
  int lh = ln >> 5;
#pragma unroll
  for (int j = 0; j < 2; ++j) {
    int col = n0 + wn * 64 + j * 32 + (ln & 31);
    float bv = HAS_BIAS ? bias[col] : 0.f;
#pragma unroll
    for (int i = 0; i < MI; ++i) {
      int rbase = m0 + wm * (MT / 2) + i * 32 + 4 * lh;
#pragma unroll
      for (int r = 0; r < 16; ++r) {
        int row = rbase + (r & 3) + 8 * (r >> 2);
        float v = acc[i][j][r] + bv;
        if (HAS_MASK) v *= mask[row];
        if (RELU) v = fmaxf(v, 0.f);
        if (OUT_BF16)
          ((bf16*)Cout)[outbase + (size_t)row * N + col] = (bf16)v;
        else
          ((float*)Cout)[outbase + (size_t)row * N + col] = v;
      }
    }
  }
}

// ---------------------------------------------------------------------------
// attended build (vectorized): att = [ctx | c2q | ctx*c2q | ctx*q2c[b]]
// ---------------------------------------------------------------------------
__global__ __launch_bounds__(256) void attbuild_kernel(
    const float* __restrict__ ctx, const bf16* __restrict__ c2q,
    const float* __restrict__ q2c, bf16* __restrict__ att) {
  int idx = blockIdx.x * 256 + threadIdx.x;
  int row = idx >> 7;
  int e = (idx & 127) * 4;
  int b = row >> 10;
  float4 cv = *(const float4*)&ctx[(size_t)row * EE + e];
  bf16x4 qv = *(const bf16x4*)&c2q[(size_t)row * EE + e];
  float4 gv = *(const float4*)&q2c[b * EE + e];
  bf16* dst = att + (size_t)row * FOURE;
  bf16x4 o0, o2, o3;
  o0[0] = (bf16)cv.x; o0[1] = (bf16)cv.y; o0[2] = (bf16)cv.z; o0[3] = (bf16)cv.w;
  o2[0] = (bf16)(cv.x * (float)qv[0]); o2[1] = (bf16)(cv.y * (float)qv[1]);
  o2[2] = (bf16)(cv.z * (float)qv[2]); o2[3] = (bf16)(cv.w * (float)qv[3]);
  o3[0] = (bf16)(cv.x * gv.x); o3[1] = (bf16)(cv.y * gv.y);
  o3[2] = (bf16)(cv.z * gv.z); o3[3] = (bf16)(cv.w * gv.w);
  *(bf16x4*)&dst[e] = o0;
  *(bf16x4*)&dst[512 + e] = qv;
  *(bf16x4*)&dst[1024 + e] = o2;
  *(bf16x4*)&dst[1536 + e] = o3;
}

// ---------------------------------------------------------------------------
// launcher — 8 dispatches (incl. memset)
// ---------------------------------------------------------------------------
extern "C" void kernel_launch(void* const* d_in, const int* in_sizes, int n_in,
                              void* d_out, int out_size, void* d_ws, size_t ws_size,
                              hipStream_t stream) {
  const float* ctx = (const float*)d_in[0];
  const float* qst = (const float*)d_in[1];
  const float* mask = (const float*)d_in[2];
  const float* wqv = (const float*)d_in[3];
  const float* wcv = (const float*)d_in[4];
  const float* wmul = (const float*)d_in[5];
  const float* W1 = (const float*)d_in[6];
  const float* b1 = (const float*)d_in[7];
  const float* W2 = (const float*)d_in[8];
  const float* b2 = (const float*)d_in[9];
  float* out = (float*)d_out;
  char* ws = (char*)d_ws;

  bf16* att = (bf16*)(ws);                  // 33554432
  bf16* hbuf = (bf16*)(ws + 33554432);      // 16777216
  bf16* W1T = (bf16*)(ws + 50331648);       // 4194304
  bf16* W2T = (bf16*)(ws + 54525952);       // 4194304
  bf16* qT = (bf16*)(ws + 58720256);        // 1048576
  bf16* P = (bf16*)(ws + 59768832);         // 2097152
  bf16* c2q = (bf16*)(ws + 61865984);       // 8388608
  bf16* qmh = (bf16*)(ws + 70254592);       // 1048576
  bf16* qml = (bf16*)(ws + 71303168);       // 1048576
  float* smax = (float*)(ws + 72351744);    // 32768
  float* q2c = (float*)(ws + 72384512);     // 16384
  float* qw = (float*)(ws + 72400896);      // 4096

  prep_kernel<<<5120, 256, 0, stream>>>(W1, W2, qst, wmul, wqv,
                                        W1T, W2T, qT, qmh, qml, qw);
  sim_kernel<<<dim3(16, BB), 256, 0, stream>>>(ctx, qmh, qml, wcv, qw, P, smax);
  hipMemsetAsync(q2c, 0, BB * EE * sizeof(float), stream);
  q2c_kernel<<<256, 256, 0, stream>>>(ctx, smax, q2c);
  gemm_bt_kernel<128, 1, 0, 0, 0><<<dim3(32, BB), 256, 0, stream>>>(
      P, qT, nullptr, nullptr, c2q, 1024, 512, 128,
      (long)CC * QQ, (long)EE * QQ, (long)CC * EE);
  attbuild_kernel<<<4096, 256, 0, stream>>>(ctx, c2q, q2c, att);
  gemm_bt_kernel<64, 1, 0, 1, 1><<<dim3(1024, 1), 256, 0, stream>>>(
      att, W1T, b1, mask, hbuf, 8192, 1024, 2048, 0, 0, 0);
  gemm_bt_kernel<128, 0, 1, 1, 1><<<dim3(1024, 1), 256, 0, stream>>>(
      hbuf, W2T, b2, mask, out, 8192, 2048, 1024, 0, 0, 0);
}